// Round 6
// baseline (146.641 us; speedup 1.0000x reference)
//
#include <hip/hip_runtime.h>
#include <math.h>

// Problem constants
#define DM   512
#define NH   8
#define HD   64
#define B_   2
#define L_   1024
#define M_   (B_ * L_)   // 2048 rows

typedef __attribute__((ext_vector_type(8))) short  bfrag;   // 8 bf16 (4 VGPRs, 16 B)
typedef __attribute__((ext_vector_type(4))) float  fv4;     // MFMA acc
typedef __attribute__((ext_vector_type(4))) unsigned short usv4;  // 8 B
typedef __attribute__((ext_vector_type(8))) unsigned short usv8;  // 16 B

__device__ __forceinline__ unsigned short f32_bf16_rne(float f) {
    unsigned u = __float_as_uint(f);
    unsigned r = u + 0x7FFF + ((u >> 16) & 1);
    return (unsigned short)(r >> 16);
}
__device__ __forceinline__ float bf16_f32(unsigned short h) {
    return __uint_as_float(((unsigned)h) << 16);
}

// ---------------- prep: fp32 -> (hi, lo) bf16 for x and all 4 weights ----------
__global__ __launch_bounds__(256) void prep_kernel(
    const float* __restrict__ x,
    const float* __restrict__ Wq, const float* __restrict__ Wk,
    const float* __restrict__ Wv, const float* __restrict__ Wo,
    unsigned short* __restrict__ xh, unsigned short* __restrict__ xl,
    unsigned short* __restrict__ wh, unsigned short* __restrict__ wl) {
    int bid = blockIdx.x;
    const float* src; unsigned short *dh, *dl; size_t off;
    if (bid < 1024) {
        src = x; dh = xh; dl = xl; off = (size_t)bid * 1024;
    } else {
        int wsel = (bid - 1024) >> 8;
        int wb   = (bid - 1024) & 255;
        src = (wsel == 0) ? Wq : (wsel == 1) ? Wk : (wsel == 2) ? Wv : Wo;
        dh = wh + (size_t)wsel * 262144;
        dl = wl + (size_t)wsel * 262144;
        off = (size_t)wb * 1024;
    }
    size_t i = off + (size_t)threadIdx.x * 4;
    float4 v = *(const float4*)(src + i);
    usv4 h, l;
    h.x = f32_bf16_rne(v.x); l.x = f32_bf16_rne(v.x - bf16_f32(h.x));
    h.y = f32_bf16_rne(v.y); l.y = f32_bf16_rne(v.y - bf16_f32(h.y));
    h.z = f32_bf16_rne(v.z); l.z = f32_bf16_rne(v.z - bf16_f32(h.z));
    h.w = f32_bf16_rne(v.w); l.w = f32_bf16_rne(v.w - bf16_f32(h.w));
    *(usv4*)(dh + i) = h;
    *(usv4*)(dl + i) = l;
}

// ---------------- split-bf16 MFMA GEMM on pre-converted inputs ----------------
// C = A @ W^T + bias (optionally exp()). A: (M,512) hi/lo bf16, W: (512,512) hi/lo.
// C-tile 128 x TNv, 256 threads = 4 waves; wave w covers rows w*32..w*32+31 as
// 2 x (TNv/16) frags of 16x16x32, 3 MFMA passes (Markidis split) per frag.
#define TM 128
#define TK 32
// LDS row stride in shorts: MUST be a multiple of 8 shorts (16 B) so b128 frag
// reads at row*LDA + quad*8 stay 16B-aligned (round-3 NaN #1). Staging chunks
// are 8 shorts = 16 B -> usv8 only (round-4 NaN #2).
#define LDA 40

template <int TNv>
__device__ __forceinline__ void mfma_gemm_bf16(
    const unsigned short* __restrict__ Ahg, const unsigned short* __restrict__ Alg,
    const unsigned short* __restrict__ Bhg, const unsigned short* __restrict__ Blg,
    const float* __restrict__ bias, float* __restrict__ C, int do_exp) {
    constexpr int NF  = TNv / 16;        // B col-frags per wave
    constexpr int BCH = TNv * 4 / 256;   // B staging chunks per thread

    __shared__ __align__(16) unsigned short Ah[TM * LDA];
    __shared__ __align__(16) unsigned short Al[TM * LDA];
    __shared__ __align__(16) unsigned short Bh[TNv * LDA];
    __shared__ __align__(16) unsigned short Bl[TNv * LDA];

    const int tid  = threadIdx.x;
    const int wave = tid >> 6, lane = tid & 63;
    const int quad = lane >> 4, r16 = lane & 15;
    const int m0 = blockIdx.y * TM, n0 = blockIdx.x * TNv;

    fv4 acc[2][NF] = {};

    for (int k0 = 0; k0 < DM; k0 += TK) {
        // A: 128 rows x 4 chunks(16 B) = 512 chunks -> 2/thread (hi & lo)
#pragma unroll
        for (int t = 0; t < 2; ++t) {
            int idx = tid + t * 256;
            int row = idx >> 2, ch = (idx & 3) << 3;          // ch in shorts
            size_t g = (size_t)(m0 + row) * DM + k0 + ch;
            *(usv8*)(Ah + row * LDA + ch) = *(const usv8*)(Ahg + g);
            *(usv8*)(Al + row * LDA + ch) = *(const usv8*)(Alg + g);
        }
        // B: TNv rows x 4 chunks -> BCH/thread (hi & lo)
#pragma unroll
        for (int t = 0; t < BCH; ++t) {
            int idx = tid + t * 256;
            int row = idx >> 2, ch = (idx & 3) << 3;
            size_t g = (size_t)(n0 + row) * DM + k0 + ch;
            *(usv8*)(Bh + row * LDA + ch) = *(const usv8*)(Bhg + g);
            *(usv8*)(Bl + row * LDA + ch) = *(const usv8*)(Blg + g);
        }
        __syncthreads();

        bfrag ah[2], al[2], bh[NF], bl[NF];
#pragma unroll
        for (int i = 0; i < 2; ++i) {
            int off = (wave * 32 + i * 16 + r16) * LDA + quad * 8;
            ah[i] = *(const bfrag*)(Ah + off);
            al[i] = *(const bfrag*)(Al + off);
        }
#pragma unroll
        for (int j = 0; j < NF; ++j) {
            int off = (j * 16 + r16) * LDA + quad * 8;
            bh[j] = *(const bfrag*)(Bh + off);
            bl[j] = *(const bfrag*)(Bl + off);
        }

#pragma unroll
        for (int i = 0; i < 2; ++i)
#pragma unroll
            for (int j = 0; j < NF; ++j) {
                acc[i][j] = __builtin_amdgcn_mfma_f32_16x16x32_bf16(ah[i], bh[j], acc[i][j], 0, 0, 0);
                acc[i][j] = __builtin_amdgcn_mfma_f32_16x16x32_bf16(ah[i], bl[j], acc[i][j], 0, 0, 0);
                acc[i][j] = __builtin_amdgcn_mfma_f32_16x16x32_bf16(al[i], bh[j], acc[i][j], 0, 0, 0);
            }
        __syncthreads();
    }

    // epilogue: D[row = quad*4 + r][col = r16]
#pragma unroll
    for (int j = 0; j < NF; ++j) {
        int n = n0 + j * 16 + r16;
        float bn = bias[n];
#pragma unroll
        for (int i = 0; i < 2; ++i) {
#pragma unroll
            for (int r = 0; r < 4; ++r) {
                int m = m0 + wave * 32 + i * 16 + quad * 4 + r;
                float v = acc[i][j][r] + bn;
                if (do_exp) v = __expf(v);
                C[(size_t)m * DM + n] = v;
            }
        }
    }
}

// QKV: 128x128 tiles. z=0 -> exp(Q), z=1 -> exp(K), z=2 -> V
__global__ __launch_bounds__(256, 2) void gemm_qkv_kernel(
    const unsigned short* __restrict__ xh, const unsigned short* __restrict__ xl,
    const unsigned short* __restrict__ wh, const unsigned short* __restrict__ wl,
    const float* __restrict__ bq, const float* __restrict__ bk, const float* __restrict__ bv,
    float* __restrict__ Qe, float* __restrict__ Ke, float* __restrict__ V) {
    int z = blockIdx.z;
    const float* b = (z == 0) ? bq : (z == 1) ? bk : bv;
    float* C = (z == 0) ? Qe : (z == 1) ? Ke : V;
    mfma_gemm_bf16<128>(xh, xl, wh + (size_t)z * 262144, wl + (size_t)z * 262144,
                        b, C, z < 2);
}

__global__ __launch_bounds__(256) void gemm_out_kernel(
    const unsigned short* __restrict__ jh, const unsigned short* __restrict__ jl,
    const unsigned short* __restrict__ wh, const unsigned short* __restrict__ wl,
    const float* __restrict__ bo, float* __restrict__ C) {
    mfma_gemm_bf16<64>(jh, jl, wh + (size_t)3 * 262144, wl + (size_t)3 * 262144,
                       bo, C, 0);
}

// ---------------- KV stats: partial S[d,e] and z[d] per (bh, split) ----------------
// Kbuf already holds exp(K). LDS rows padded to 68 floats (272 B, 16B-aligned)
// so float4 LDS ops stay aligned.
#define JT 64
__global__ __launch_bounds__(256) void kv_stats_kernel(
    const float* __restrict__ Kbuf, const float* __restrict__ Vbuf,
    float* __restrict__ Spart, float* __restrict__ zpart) {
    const int split = blockIdx.x, bh = blockIdx.y;
    const int b = bh >> 3, h = bh & 7;
    const int j0 = split * JT;

    __shared__ __align__(16) float EK[JT][HD + 4];
    __shared__ __align__(16) float VS[JT][HD + 4];

    const int tid = threadIdx.x;
#pragma unroll
    for (int t = 0; t < 4; ++t) {
        int idx = tid + t * 256;
        int r = idx >> 4;
        int c = (idx & 15) << 2;
        size_t row = (size_t)(b * L_ + j0 + r) * DM + h * HD + c;
        float4 kv = *(const float4*)(Kbuf + row);
        *(float4*)&EK[r][c] = kv;
        float4 vv = *(const float4*)(Vbuf + row);
        *(float4*)&VS[r][c] = vv;
    }
    __syncthreads();

    const int tx = tid & 15, ty = tid >> 4;
    float acc[4][4] = {{0.f}};
#pragma unroll 8
    for (int jj = 0; jj < JT; ++jj) {
        float4 ek = *(const float4*)&EK[jj][ty * 4];
        float4 vs = *(const float4*)&VS[jj][tx * 4];
        float e[4] = {ek.x, ek.y, ek.z, ek.w};
        float v[4] = {vs.x, vs.y, vs.z, vs.w};
#pragma unroll
        for (int i = 0; i < 4; ++i)
#pragma unroll
            for (int j = 0; j < 4; ++j) acc[i][j] += e[i] * v[j];
    }

    float* sp = Spart + ((size_t)bh * 16 + split) * (HD * HD);
#pragma unroll
    for (int i = 0; i < 4; ++i) {
        float4 o; o.x = acc[i][0]; o.y = acc[i][1]; o.z = acc[i][2]; o.w = acc[i][3];
        *(float4*)(sp + (ty * 4 + i) * HD + tx * 4) = o;
    }
    if (tid < HD) {
        float z = 0.f;
#pragma unroll 8
        for (int jj = 0; jj < JT; ++jj) z += EK[jj][tid];
        zpart[((size_t)bh * 16 + split) * HD + tid] = z;
    }
}

// ---------------- heads: numer/denom per query row; writes joined as hi/lo bf16 ----
// Qbuf already holds exp(Q).
__global__ __launch_bounds__(256) void heads_kernel(
    const float* __restrict__ Qbuf, const float* __restrict__ Spart,
    const float* __restrict__ zpart,
    unsigned short* __restrict__ jh, unsigned short* __restrict__ jl) {
    const int tileI = blockIdx.x, bh = blockIdx.y;
    const int b = bh >> 3, h = bh & 7;

    __shared__ __align__(16) float S[HD][HD + 4];
    __shared__ float zl[HD];

    const int tid = threadIdx.x;
    // reduce 16 S partials, float4-vectorized: 1024 float4 -> 4/thread
#pragma unroll
    for (int t = 0; t < 4; ++t) {
        int idx4 = tid + t * 256;              // 0..1023 (float4 index)
        const float* sp = Spart + (size_t)bh * 16 * (HD * HD) + (size_t)idx4 * 4;
        float4 s = {0.f, 0.f, 0.f, 0.f};
#pragma unroll
        for (int p = 0; p < 16; ++p) {
            float4 v = *(const float4*)(sp + (size_t)p * (HD * HD));
            s.x += v.x; s.y += v.y; s.z += v.z; s.w += v.w;
        }
        int row = idx4 >> 4, col = (idx4 & 15) << 2;
        *(float4*)&S[row][col] = s;
    }
    if (tid < HD) {
        float z = 0.f;
        const float* zp = zpart + (size_t)bh * 16 * HD + tid;
#pragma unroll
        for (int p = 0; p < 16; ++p) z += zp[(size_t)p * HD];
        zl[tid] = z;
    }
    __syncthreads();

    const int lane = tid & 63, w = tid >> 6;
#pragma unroll 1
    for (int r = 0; r < 16; ++r) {
        int i = tileI * 64 + w * 16 + r;
        float eq = Qbuf[(size_t)(b * L_ + i) * DM + h * HD + lane];

        float denom = eq * zl[lane];
#pragma unroll
        for (int off = 32; off; off >>= 1) denom += __shfl_xor(denom, off, 64);

        float acc = 0.f;
#pragma unroll
        for (int d = 0; d < HD; ++d) {
            float bq = __shfl(eq, d, 64);
            acc += bq * S[d][lane];
        }
        float val = acc / denom;
        size_t oidx = (size_t)(b * L_ + i) * DM + h * HD + lane;
        unsigned short hh = f32_bf16_rne(val);
        unsigned short ll = f32_bf16_rne(val - bf16_f32(hh));
        jh[oidx] = hh;
        jl[oidx] = ll;
    }
}

// ---------------- launch ----------------
extern "C" void kernel_launch(void* const* d_in, const int* in_sizes, int n_in,
                              void* d_out, int out_size, void* d_ws, size_t ws_size,
                              hipStream_t stream) {
    const float* x  = (const float*)d_in[0];
    const float* Wq = (const float*)d_in[1];
    const float* bq = (const float*)d_in[2];
    const float* Wk = (const float*)d_in[3];
    const float* bk = (const float*)d_in[4];
    const float* Wv = (const float*)d_in[5];
    const float* bv = (const float*)d_in[6];
    const float* Wo = (const float*)d_in[7];
    const float* bo = (const float*)d_in[8];
    float* out = (float*)d_out;

    float* f = (float*)d_ws;
    const size_t NQ = (size_t)M_ * DM;               // 1,048,576
    float* Qe    = f;
    float* Ke    = f + NQ;
    float* V     = f + 2 * NQ;
    float* Spart = f + 3 * NQ;                        // 16*16*4096 = 1M floats
    float* zpart = f + 4 * NQ;                        // 16K floats
    unsigned short* u = (unsigned short*)(f + 4 * NQ + 16384);
    unsigned short* xh = u;
    unsigned short* xl = u + NQ;
    unsigned short* wh = u + 2 * NQ;                  // 4 x 262144
    unsigned short* wl = u + 3 * NQ;
    unsigned short* jh = u + 4 * NQ;
    unsigned short* jl = u + 5 * NQ;

    prep_kernel<<<2048, 256, 0, stream>>>(x, Wq, Wk, Wv, Wo, xh, xl, wh, wl);

    dim3 gQKV(DM / 128, M_ / TM, 3);   // (4, 16, 3) = 192 blocks
    gemm_qkv_kernel<<<gQKV, 256, 0, stream>>>(xh, xl, wh, wl, bq, bk, bv, Qe, Ke, V);

    kv_stats_kernel<<<dim3(16, 16), 256, 0, stream>>>(Ke, V, Spart, zpart);

    heads_kernel<<<dim3(16, 16), 256, 0, stream>>>(Qe, Spart, zpart, jh, jl);

    dim3 gO(DM / 64, M_ / TM, 1);      // (8, 16) = 128 blocks
    gemm_out_kernel<<<gO, 256, 0, stream>>>(jh, jl, wh, wl, bo, out);
}

// Round 7
// 141.032 us; speedup vs baseline: 1.0398x; 1.0398x over previous
//
#include <hip/hip_runtime.h>
#include <math.h>

// Problem constants
#define DM   512
#define NH   8
#define HD   64
#define B_   2
#define L_   1024
#define M_   (B_ * L_)   // 2048 rows

typedef __attribute__((ext_vector_type(8))) short  bfrag;   // 8 bf16 (4 VGPRs, 16 B)
typedef __attribute__((ext_vector_type(4))) float  fv4;     // MFMA acc
typedef __attribute__((ext_vector_type(4))) unsigned short usv4;  // 8 B
typedef __attribute__((ext_vector_type(8))) unsigned short usv8;  // 16 B

__device__ __forceinline__ unsigned short f32_bf16_rne(float f) {
    unsigned u = __float_as_uint(f);
    unsigned r = u + 0x7FFF + ((u >> 16) & 1);
    return (unsigned short)(r >> 16);
}
__device__ __forceinline__ float bf16_f32(unsigned short h) {
    return __uint_as_float(((unsigned)h) << 16);
}

// ---------------- prep: fp32 -> (hi, lo) bf16 for x and all 4 weights ----------
__global__ __launch_bounds__(256) void prep_kernel(
    const float* __restrict__ x,
    const float* __restrict__ Wq, const float* __restrict__ Wk,
    const float* __restrict__ Wv, const float* __restrict__ Wo,
    unsigned short* __restrict__ xh, unsigned short* __restrict__ xl,
    unsigned short* __restrict__ wh, unsigned short* __restrict__ wl) {
    int bid = blockIdx.x;
    const float* src; unsigned short *dh, *dl; size_t off;
    if (bid < 1024) {
        src = x; dh = xh; dl = xl; off = (size_t)bid * 1024;
    } else {
        int wsel = (bid - 1024) >> 8;
        int wb   = (bid - 1024) & 255;
        src = (wsel == 0) ? Wq : (wsel == 1) ? Wk : (wsel == 2) ? Wv : Wo;
        dh = wh + (size_t)wsel * 262144;
        dl = wl + (size_t)wsel * 262144;
        off = (size_t)wb * 1024;
    }
    size_t i = off + (size_t)threadIdx.x * 4;
    float4 v = *(const float4*)(src + i);
    usv4 h, l;
    h.x = f32_bf16_rne(v.x); l.x = f32_bf16_rne(v.x - bf16_f32(h.x));
    h.y = f32_bf16_rne(v.y); l.y = f32_bf16_rne(v.y - bf16_f32(h.y));
    h.z = f32_bf16_rne(v.z); l.z = f32_bf16_rne(v.z - bf16_f32(h.z));
    h.w = f32_bf16_rne(v.w); l.w = f32_bf16_rne(v.w - bf16_f32(h.w));
    *(usv4*)(dh + i) = h;
    *(usv4*)(dl + i) = l;
}

// ---------------- split-bf16 MFMA GEMM on pre-converted inputs ----------------
// C = A @ W^T + bias (optionally exp()). A: (M,512) hi/lo bf16, W: (512,512) hi/lo.
// C-tile 128x64, 256 threads = 4 waves; wave w covers rows w*32..w*32+31 as
// 2x4 frags of 16x16x32, 3 MFMA passes (Markidis split) per frag.
// Tile choice: 128x64 -> QKV grid (8,16,3)=384 blocks (oversubscribes 256 CUs).
// 128x128 (192 blocks) measured SLOWER (r6: 146.6 vs 142.5) — under-occupancy.
#define TM 128
#define TN 64
#define TK 32
// LDS row stride in shorts: MUST be a multiple of 8 shorts (16 B) so b128 frag
// reads at row*LDA + quad*8 stay 16B-aligned (round-3 NaN #1). Staging chunks
// are 8 shorts = 16 B -> usv8 only (round-4 NaN #2).
#define LDA 40

__device__ __forceinline__ void mfma_gemm_bf16(
    const unsigned short* __restrict__ Ahg, const unsigned short* __restrict__ Alg,
    const unsigned short* __restrict__ Bhg, const unsigned short* __restrict__ Blg,
    const float* __restrict__ bias, float* __restrict__ C, int do_exp) {
    __shared__ __align__(16) unsigned short Ah[TM * LDA];
    __shared__ __align__(16) unsigned short Al[TM * LDA];
    __shared__ __align__(16) unsigned short Bh[TN * LDA];
    __shared__ __align__(16) unsigned short Bl[TN * LDA];

    const int tid  = threadIdx.x;
    const int wave = tid >> 6, lane = tid & 63;
    const int quad = lane >> 4, r16 = lane & 15;
    const int m0 = blockIdx.y * TM, n0 = blockIdx.x * TN;

    fv4 acc[2][4] = {};

    for (int k0 = 0; k0 < DM; k0 += TK) {
        // A: 128 rows x 4 chunks(8 shorts = 16 B) = 512 chunks -> 2/thread (hi & lo)
#pragma unroll
        for (int t = 0; t < 2; ++t) {
            int idx = tid + t * 256;
            int row = idx >> 2, ch = (idx & 3) << 3;          // ch in shorts
            size_t g = (size_t)(m0 + row) * DM + k0 + ch;
            *(usv8*)(Ah + row * LDA + ch) = *(const usv8*)(Ahg + g);
            *(usv8*)(Al + row * LDA + ch) = *(const usv8*)(Alg + g);
        }
        // B: 64 rows x 4 chunks = 256 chunks -> 1/thread (hi & lo)
        {
            int row = tid >> 2, ch = (tid & 3) << 3;
            size_t g = (size_t)(n0 + row) * DM + k0 + ch;
            *(usv8*)(Bh + row * LDA + ch) = *(const usv8*)(Bhg + g);
            *(usv8*)(Bl + row * LDA + ch) = *(const usv8*)(Blg + g);
        }
        __syncthreads();

        bfrag ah[2], al[2], bh[4], bl[4];
#pragma unroll
        for (int i = 0; i < 2; ++i) {
            int off = (wave * 32 + i * 16 + r16) * LDA + quad * 8;
            ah[i] = *(const bfrag*)(Ah + off);
            al[i] = *(const bfrag*)(Al + off);
        }
#pragma unroll
        for (int j = 0; j < 4; ++j) {
            int off = (j * 16 + r16) * LDA + quad * 8;
            bh[j] = *(const bfrag*)(Bh + off);
            bl[j] = *(const bfrag*)(Bl + off);
        }

#pragma unroll
        for (int i = 0; i < 2; ++i)
#pragma unroll
            for (int j = 0; j < 4; ++j) {
                acc[i][j] = __builtin_amdgcn_mfma_f32_16x16x32_bf16(ah[i], bh[j], acc[i][j], 0, 0, 0);
                acc[i][j] = __builtin_amdgcn_mfma_f32_16x16x32_bf16(ah[i], bl[j], acc[i][j], 0, 0, 0);
                acc[i][j] = __builtin_amdgcn_mfma_f32_16x16x32_bf16(al[i], bh[j], acc[i][j], 0, 0, 0);
            }
        __syncthreads();
    }

    // epilogue: D[row = quad*4 + r][col = r16]
#pragma unroll
    for (int j = 0; j < 4; ++j) {
        int n = n0 + j * 16 + r16;
        float bn = bias[n];
#pragma unroll
        for (int i = 0; i < 2; ++i) {
#pragma unroll
            for (int r = 0; r < 4; ++r) {
                int m = m0 + wave * 32 + i * 16 + quad * 4 + r;
                float v = acc[i][j][r] + bn;
                if (do_exp) v = __expf(v);
                C[(size_t)m * DM + n] = v;
            }
        }
    }
}

// QKV: z=0 -> exp(Q), z=1 -> exp(K), z=2 -> V
__global__ __launch_bounds__(256) void gemm_qkv_kernel(
    const unsigned short* __restrict__ xh, const unsigned short* __restrict__ xl,
    const unsigned short* __restrict__ wh, const unsigned short* __restrict__ wl,
    const float* __restrict__ bq, const float* __restrict__ bk, const float* __restrict__ bv,
    float* __restrict__ Qe, float* __restrict__ Ke, float* __restrict__ V) {
    int z = blockIdx.z;
    const float* b = (z == 0) ? bq : (z == 1) ? bk : bv;
    float* C = (z == 0) ? Qe : (z == 1) ? Ke : V;
    mfma_gemm_bf16(xh, xl, wh + (size_t)z * 262144, wl + (size_t)z * 262144,
                   b, C, z < 2);
}

__global__ __launch_bounds__(256) void gemm_out_kernel(
    const unsigned short* __restrict__ jh, const unsigned short* __restrict__ jl,
    const unsigned short* __restrict__ wh, const unsigned short* __restrict__ wl,
    const float* __restrict__ bo, float* __restrict__ C) {
    mfma_gemm_bf16(jh, jl, wh + (size_t)3 * 262144, wl + (size_t)3 * 262144,
                   bo, C, 0);
}

// ---------------- KV stats: partial S[d,e] and z[d] per (bh, split) ----------------
// Kbuf already holds exp(K). LDS rows padded to 68 floats (272 B, 16B-aligned).
#define JT 64
__global__ __launch_bounds__(256) void kv_stats_kernel(
    const float* __restrict__ Kbuf, const float* __restrict__ Vbuf,
    float* __restrict__ Spart, float* __restrict__ zpart) {
    const int split = blockIdx.x, bh = blockIdx.y;
    const int b = bh >> 3, h = bh & 7;
    const int j0 = split * JT;

    __shared__ __align__(16) float EK[JT][HD + 4];
    __shared__ __align__(16) float VS[JT][HD + 4];

    const int tid = threadIdx.x;
#pragma unroll
    for (int t = 0; t < 4; ++t) {
        int idx = tid + t * 256;
        int r = idx >> 4;
        int c = (idx & 15) << 2;
        size_t row = (size_t)(b * L_ + j0 + r) * DM + h * HD + c;
        *(float4*)&EK[r][c] = *(const float4*)(Kbuf + row);
        *(float4*)&VS[r][c] = *(const float4*)(Vbuf + row);
    }
    __syncthreads();

    const int tx = tid & 15, ty = tid >> 4;
    float acc[4][4] = {{0.f}};
#pragma unroll 8
    for (int jj = 0; jj < JT; ++jj) {
        float4 ek = *(const float4*)&EK[jj][ty * 4];
        float4 vs = *(const float4*)&VS[jj][tx * 4];
        float e[4] = {ek.x, ek.y, ek.z, ek.w};
        float v[4] = {vs.x, vs.y, vs.z, vs.w};
#pragma unroll
        for (int i = 0; i < 4; ++i)
#pragma unroll
            for (int j = 0; j < 4; ++j) acc[i][j] += e[i] * v[j];
    }

    float* sp = Spart + ((size_t)bh * 16 + split) * (HD * HD);
#pragma unroll
    for (int i = 0; i < 4; ++i) {
        float4 o; o.x = acc[i][0]; o.y = acc[i][1]; o.z = acc[i][2]; o.w = acc[i][3];
        *(float4*)(sp + (ty * 4 + i) * HD + tx * 4) = o;
    }
    if (tid < HD) {
        float z = 0.f;
#pragma unroll 8
        for (int jj = 0; jj < JT; ++jj) z += EK[jj][tid];
        zpart[((size_t)bh * 16 + split) * HD + tid] = z;
    }
}

// ---------------- heads: numer/denom per query row; writes joined as hi/lo bf16 ----
// Qbuf already holds exp(Q).
__global__ __launch_bounds__(256) void heads_kernel(
    const float* __restrict__ Qbuf, const float* __restrict__ Spart,
    const float* __restrict__ zpart,
    unsigned short* __restrict__ jh, unsigned short* __restrict__ jl) {
    const int tileI = blockIdx.x, bh = blockIdx.y;
    const int b = bh >> 3, h = bh & 7;

    __shared__ __align__(16) float S[HD][HD + 4];
    __shared__ float zl[HD];

    const int tid = threadIdx.x;
    // reduce 16 S partials, float4-vectorized: 1024 float4 -> 4/thread
#pragma unroll
    for (int t = 0; t < 4; ++t) {
        int idx4 = tid + t * 256;              // 0..1023 (float4 index)
        const float* sp = Spart + (size_t)bh * 16 * (HD * HD) + (size_t)idx4 * 4;
        float4 s = {0.f, 0.f, 0.f, 0.f};
#pragma unroll
        for (int p = 0; p < 16; ++p) {
            float4 v = *(const float4*)(sp + (size_t)p * (HD * HD));
            s.x += v.x; s.y += v.y; s.z += v.z; s.w += v.w;
        }
        int row = idx4 >> 4, col = (idx4 & 15) << 2;
        *(float4*)&S[row][col] = s;
    }
    if (tid < HD) {
        float z = 0.f;
        const float* zp = zpart + (size_t)bh * 16 * HD + tid;
#pragma unroll
        for (int p = 0; p < 16; ++p) z += zp[(size_t)p * HD];
        zl[tid] = z;
    }
    __syncthreads();

    const int lane = tid & 63, w = tid >> 6;
#pragma unroll 1
    for (int r = 0; r < 16; ++r) {
        int i = tileI * 64 + w * 16 + r;
        float eq = Qbuf[(size_t)(b * L_ + i) * DM + h * HD + lane];

        float denom = eq * zl[lane];
#pragma unroll
        for (int off = 32; off; off >>= 1) denom += __shfl_xor(denom, off, 64);

        float acc = 0.f;
#pragma unroll
        for (int d = 0; d < HD; ++d) {
            float bq = __shfl(eq, d, 64);
            acc += bq * S[d][lane];
        }
        float val = acc / denom;
        size_t oidx = (size_t)(b * L_ + i) * DM + h * HD + lane;
        unsigned short hh = f32_bf16_rne(val);
        unsigned short ll = f32_bf16_rne(val - bf16_f32(hh));
        jh[oidx] = hh;
        jl[oidx] = ll;
    }
}

// ---------------- launch ----------------
extern "C" void kernel_launch(void* const* d_in, const int* in_sizes, int n_in,
                              void* d_out, int out_size, void* d_ws, size_t ws_size,
                              hipStream_t stream) {
    const float* x  = (const float*)d_in[0];
    const float* Wq = (const float*)d_in[1];
    const float* bq = (const float*)d_in[2];
    const float* Wk = (const float*)d_in[3];
    const float* bk = (const float*)d_in[4];
    const float* Wv = (const float*)d_in[5];
    const float* bv = (const float*)d_in[6];
    const float* Wo = (const float*)d_in[7];
    const float* bo = (const float*)d_in[8];
    float* out = (float*)d_out;

    float* f = (float*)d_ws;
    const size_t NQ = (size_t)M_ * DM;               // 1,048,576
    float* Qe    = f;
    float* Ke    = f + NQ;
    float* V     = f + 2 * NQ;
    float* Spart = f + 3 * NQ;                        // 16*16*4096 = 1M floats
    float* zpart = f + 4 * NQ;                        // 16K floats
    unsigned short* u = (unsigned short*)(f + 4 * NQ + 16384);
    unsigned short* xh = u;
    unsigned short* xl = u + NQ;
    unsigned short* wh = u + 2 * NQ;                  // 4 x 262144
    unsigned short* wl = u + 3 * NQ;
    unsigned short* jh = u + 4 * NQ;
    unsigned short* jl = u + 5 * NQ;

    prep_kernel<<<2048, 256, 0, stream>>>(x, Wq, Wk, Wv, Wo, xh, xl, wh, wl);

    dim3 gQKV(DM / TN, M_ / TM, 3);   // (8, 16, 3) = 384 blocks
    gemm_qkv_kernel<<<gQKV, 256, 0, stream>>>(xh, xl, wh, wl, bq, bk, bv, Qe, Ke, V);

    kv_stats_kernel<<<dim3(16, 16), 256, 0, stream>>>(Ke, V, Spart, zpart);

    heads_kernel<<<dim3(16, 16), 256, 0, stream>>>(Qe, Spart, zpart, jh, jl);

    dim3 gO(DM / TN, M_ / TM, 1);     // (8, 16) = 128 blocks
    gemm_out_kernel<<<gO, 256, 0, stream>>>(jh, jl, wh, wl, bo, out);
}

// Round 8
// 139.896 us; speedup vs baseline: 1.0482x; 1.0081x over previous
//
#include <hip/hip_runtime.h>
#include <math.h>

// Problem constants
#define DM   512
#define NH   8
#define HD   64
#define B_   2
#define L_   1024
#define M_   (B_ * L_)   // 2048 rows

typedef __attribute__((ext_vector_type(8))) short  bfrag;   // 8 bf16 (4 VGPRs, 16 B)
typedef __attribute__((ext_vector_type(4))) float  fv4;     // MFMA acc
typedef __attribute__((ext_vector_type(4))) unsigned short usv4;  // 8 B

__device__ __forceinline__ unsigned short f32_bf16_rne(float f) {
    unsigned u = __float_as_uint(f);
    unsigned r = u + 0x7FFF + ((u >> 16) & 1);
    return (unsigned short)(r >> 16);
}
__device__ __forceinline__ float bf16_f32(unsigned short h) {
    return __uint_as_float(((unsigned)h) << 16);
}

// async global->LDS, 16 B per lane. HW semantics: LDS dest = wave-uniform base
// + lane*16 (NOT per-lane scatter) -> LDS tile must be unpadded/lane-contiguous.
__device__ __forceinline__ void stage16(const unsigned short* g, unsigned short* l) {
    __builtin_amdgcn_global_load_lds(
        (const __attribute__((address_space(1))) void*)g,
        (__attribute__((address_space(3))) void*)l,
        16, 0, 0);
}

// ---------------- prep: fp32 -> (hi, lo) bf16 for x and all 4 weights ----------
__global__ __launch_bounds__(256) void prep_kernel(
    const float* __restrict__ x,
    const float* __restrict__ Wq, const float* __restrict__ Wk,
    const float* __restrict__ Wv, const float* __restrict__ Wo,
    unsigned short* __restrict__ xh, unsigned short* __restrict__ xl,
    unsigned short* __restrict__ wh, unsigned short* __restrict__ wl) {
    int bid = blockIdx.x;
    const float* src; unsigned short *dh, *dl; size_t off;
    if (bid < 1024) {
        src = x; dh = xh; dl = xl; off = (size_t)bid * 1024;
    } else {
        int wsel = (bid - 1024) >> 8;
        int wb   = (bid - 1024) & 255;
        src = (wsel == 0) ? Wq : (wsel == 1) ? Wk : (wsel == 2) ? Wv : Wo;
        dh = wh + (size_t)wsel * 262144;
        dl = wl + (size_t)wsel * 262144;
        off = (size_t)wb * 1024;
    }
    size_t i = off + (size_t)threadIdx.x * 4;
    float4 v = *(const float4*)(src + i);
    usv4 h, l;
    h.x = f32_bf16_rne(v.x); l.x = f32_bf16_rne(v.x - bf16_f32(h.x));
    h.y = f32_bf16_rne(v.y); l.y = f32_bf16_rne(v.y - bf16_f32(h.y));
    h.z = f32_bf16_rne(v.z); l.z = f32_bf16_rne(v.z - bf16_f32(h.z));
    h.w = f32_bf16_rne(v.w); l.w = f32_bf16_rne(v.w - bf16_f32(h.w));
    *(usv4*)(dh + i) = h;
    *(usv4*)(dl + i) = l;
}

// ---------------- split-bf16 MFMA GEMM, global_load_lds staging ----------------
// C = A @ W^T + bias (optionally exp()). A: (M,512) hi/lo bf16, W: (512,512) hi/lo.
// C-tile 128x64, 256 threads = 4 waves; wave w covers rows w*32..w*32+31 as
// 2x4 frags of 16x16x32, 3 MFMA passes (Markidis split) per frag.
// 128x64 -> QKV grid 384 blocks (128x128/192 blocks was SLOWER, r6: under-occupancy).
#define TM 128
#define TN 64
#define TK 32
// LDS row stride = 32 shorts (64 B), UNPADDED: global_load_lds lane-contiguity
// requires it, and b128 frag reads at row*64+quad*16 are at the LDS throughput
// floor anyway (8 lanes per 4-bank group = 8-clock min for 1 KB).
#define LDA 32

__device__ __forceinline__ void mfma_gemm_bf16(
    const unsigned short* __restrict__ Ahg, const unsigned short* __restrict__ Alg,
    const unsigned short* __restrict__ Bhg, const unsigned short* __restrict__ Blg,
    const float* __restrict__ bias, float* __restrict__ C, int do_exp) {
    __shared__ __align__(16) unsigned short Ah[TM * LDA];
    __shared__ __align__(16) unsigned short Al[TM * LDA];
    __shared__ __align__(16) unsigned short Bh[TN * LDA];
    __shared__ __align__(16) unsigned short Bl[TN * LDA];

    const int tid  = threadIdx.x;
    const int wave = tid >> 6, lane = tid & 63;
    const int quad = lane >> 4, r16 = lane & 15;
    const int m0 = blockIdx.y * TM, n0 = blockIdx.x * TN;

    // staging geometry: one wave-load = 64 lanes x 16 B = 1 chunk of 16 rows
    // x 32 shorts. lane i -> row i>>2, col (i&3)*8 shorts (= lane*16 B in LDS).
    const int srow = lane >> 2;
    const int scol = (lane & 3) << 3;

    fv4 acc[2][4] = {};

    for (int k0 = 0; k0 < DM; k0 += TK) {
        // A: 8 chunks; wave w stages chunks w and w+4 (hi & lo)
        {
            const int c1 = wave, c2 = wave + 4;
            size_t ga1 = (size_t)(m0 + c1 * 16 + srow) * DM + k0 + scol;
            size_t ga2 = (size_t)(m0 + c2 * 16 + srow) * DM + k0 + scol;
            stage16(Ahg + ga1, Ah + c1 * 512);
            stage16(Ahg + ga2, Ah + c2 * 512);
            stage16(Alg + ga1, Al + c1 * 512);
            stage16(Alg + ga2, Al + c2 * 512);
            // B: 4 chunks; wave w stages chunk w (hi & lo)
            size_t gb = (size_t)(n0 + c1 * 16 + srow) * DM + k0 + scol;
            stage16(Bhg + gb, Bh + c1 * 512);
            stage16(Blg + gb, Bl + c1 * 512);
        }
        __syncthreads();   // drains vmcnt(0) before s_barrier -> staging complete

        bfrag ah[2], al[2], bh[4], bl[4];
#pragma unroll
        for (int i = 0; i < 2; ++i) {
            int off = (wave * 32 + i * 16 + r16) * LDA + quad * 8;
            ah[i] = *(const bfrag*)(Ah + off);
            al[i] = *(const bfrag*)(Al + off);
        }
#pragma unroll
        for (int j = 0; j < 4; ++j) {
            int off = (j * 16 + r16) * LDA + quad * 8;
            bh[j] = *(const bfrag*)(Bh + off);
            bl[j] = *(const bfrag*)(Bl + off);
        }

#pragma unroll
        for (int i = 0; i < 2; ++i)
#pragma unroll
            for (int j = 0; j < 4; ++j) {
                acc[i][j] = __builtin_amdgcn_mfma_f32_16x16x32_bf16(ah[i], bh[j], acc[i][j], 0, 0, 0);
                acc[i][j] = __builtin_amdgcn_mfma_f32_16x16x32_bf16(ah[i], bl[j], acc[i][j], 0, 0, 0);
                acc[i][j] = __builtin_amdgcn_mfma_f32_16x16x32_bf16(al[i], bh[j], acc[i][j], 0, 0, 0);
            }
        __syncthreads();
    }

    // epilogue: D[row = quad*4 + r][col = r16]
#pragma unroll
    for (int j = 0; j < 4; ++j) {
        int n = n0 + j * 16 + r16;
        float bn = bias[n];
#pragma unroll
        for (int i = 0; i < 2; ++i) {
#pragma unroll
            for (int r = 0; r < 4; ++r) {
                int m = m0 + wave * 32 + i * 16 + quad * 4 + r;
                float v = acc[i][j][r] + bn;
                if (do_exp) v = __expf(v);
                C[(size_t)m * DM + n] = v;
            }
        }
    }
}

// QKV: z=0 -> exp(Q), z=1 -> exp(K), z=2 -> V
__global__ __launch_bounds__(256) void gemm_qkv_kernel(
    const unsigned short* __restrict__ xh, const unsigned short* __restrict__ xl,
    const unsigned short* __restrict__ wh, const unsigned short* __restrict__ wl,
    const float* __restrict__ bq, const float* __restrict__ bk, const float* __restrict__ bv,
    float* __restrict__ Qe, float* __restrict__ Ke, float* __restrict__ V) {
    int z = blockIdx.z;
    const float* b = (z == 0) ? bq : (z == 1) ? bk : bv;
    float* C = (z == 0) ? Qe : (z == 1) ? Ke : V;
    mfma_gemm_bf16(xh, xl, wh + (size_t)z * 262144, wl + (size_t)z * 262144,
                   b, C, z < 2);
}

__global__ __launch_bounds__(256) void gemm_out_kernel(
    const unsigned short* __restrict__ jh, const unsigned short* __restrict__ jl,
    const unsigned short* __restrict__ wh, const unsigned short* __restrict__ wl,
    const float* __restrict__ bo, float* __restrict__ C) {
    mfma_gemm_bf16(jh, jl, wh + (size_t)3 * 262144, wl + (size_t)3 * 262144,
                   bo, C, 0);
}

// ---------------- KV stats: partial S[d,e] and z[d] per (bh, split) ----------------
// Kbuf already holds exp(K). LDS rows padded to 68 floats (272 B, 16B-aligned).
#define JT 64
__global__ __launch_bounds__(256) void kv_stats_kernel(
    const float* __restrict__ Kbuf, const float* __restrict__ Vbuf,
    float* __restrict__ Spart, float* __restrict__ zpart) {
    const int split = blockIdx.x, bh = blockIdx.y;
    const int b = bh >> 3, h = bh & 7;
    const int j0 = split * JT;

    __shared__ __align__(16) float EK[JT][HD + 4];
    __shared__ __align__(16) float VS[JT][HD + 4];

    const int tid = threadIdx.x;
#pragma unroll
    for (int t = 0; t < 4; ++t) {
        int idx = tid + t * 256;
        int r = idx >> 4;
        int c = (idx & 15) << 2;
        size_t row = (size_t)(b * L_ + j0 + r) * DM + h * HD + c;
        *(float4*)&EK[r][c] = *(const float4*)(Kbuf + row);
        *(float4*)&VS[r][c] = *(const float4*)(Vbuf + row);
    }
    __syncthreads();

    const int tx = tid & 15, ty = tid >> 4;
    float acc[4][4] = {{0.f}};
#pragma unroll 8
    for (int jj = 0; jj < JT; ++jj) {
        float4 ek = *(const float4*)&EK[jj][ty * 4];
        float4 vs = *(const float4*)&VS[jj][tx * 4];
        float e[4] = {ek.x, ek.y, ek.z, ek.w};
        float v[4] = {vs.x, vs.y, vs.z, vs.w};
#pragma unroll
        for (int i = 0; i < 4; ++i)
#pragma unroll
            for (int j = 0; j < 4; ++j) acc[i][j] += e[i] * v[j];
    }

    float* sp = Spart + ((size_t)bh * 16 + split) * (HD * HD);
#pragma unroll
    for (int i = 0; i < 4; ++i) {
        float4 o; o.x = acc[i][0]; o.y = acc[i][1]; o.z = acc[i][2]; o.w = acc[i][3];
        *(float4*)(sp + (ty * 4 + i) * HD + tx * 4) = o;
    }
    if (tid < HD) {
        float z = 0.f;
#pragma unroll 8
        for (int jj = 0; jj < JT; ++jj) z += EK[jj][tid];
        zpart[((size_t)bh * 16 + split) * HD + tid] = z;
    }
}

// ---------------- heads: numer/denom per query row; writes joined as hi/lo bf16 ----
// Qbuf already holds exp(Q).
__global__ __launch_bounds__(256) void heads_kernel(
    const float* __restrict__ Qbuf, const float* __restrict__ Spart,
    const float* __restrict__ zpart,
    unsigned short* __restrict__ jh, unsigned short* __restrict__ jl) {
    const int tileI = blockIdx.x, bh = blockIdx.y;
    const int b = bh >> 3, h = bh & 7;

    __shared__ __align__(16) float S[HD][HD + 4];
    __shared__ float zl[HD];

    const int tid = threadIdx.x;
    // reduce 16 S partials, float4-vectorized: 1024 float4 -> 4/thread
#pragma unroll
    for (int t = 0; t < 4; ++t) {
        int idx4 = tid + t * 256;              // 0..1023 (float4 index)
        const float* sp = Spart + (size_t)bh * 16 * (HD * HD) + (size_t)idx4 * 4;
        float4 s = {0.f, 0.f, 0.f, 0.f};
#pragma unroll
        for (int p = 0; p < 16; ++p) {
            float4 v = *(const float4*)(sp + (size_t)p * (HD * HD));
            s.x += v.x; s.y += v.y; s.z += v.z; s.w += v.w;
        }
        int row = idx4 >> 4, col = (idx4 & 15) << 2;
        *(float4*)&S[row][col] = s;
    }
    if (tid < HD) {
        float z = 0.f;
        const float* zp = zpart + (size_t)bh * 16 * HD + tid;
#pragma unroll
        for (int p = 0; p < 16; ++p) z += zp[(size_t)p * HD];
        zl[tid] = z;
    }
    __syncthreads();

    const int lane = tid & 63, w = tid >> 6;
#pragma unroll 1
    for (int r = 0; r < 16; ++r) {
        int i = tileI * 64 + w * 16 + r;
        float eq = Qbuf[(size_t)(b * L_ + i) * DM + h * HD + lane];

        float denom = eq * zl[lane];
#pragma unroll
        for (int off = 32; off; off >>= 1) denom += __shfl_xor(denom, off, 64);

        float acc = 0.f;
#pragma unroll
        for (int d = 0; d < HD; ++d) {
            float bq = __shfl(eq, d, 64);
            acc += bq * S[d][lane];
        }
        float val = acc / denom;
        size_t oidx = (size_t)(b * L_ + i) * DM + h * HD + lane;
        unsigned short hh = f32_bf16_rne(val);
        unsigned short ll = f32_bf16_rne(val - bf16_f32(hh));
        jh[oidx] = hh;
        jl[oidx] = ll;
    }
}

// ---------------- launch ----------------
extern "C" void kernel_launch(void* const* d_in, const int* in_sizes, int n_in,
                              void* d_out, int out_size, void* d_ws, size_t ws_size,
                              hipStream_t stream) {
    const float* x  = (const float*)d_in[0];
    const float* Wq = (const float*)d_in[1];
    const float* bq = (const float*)d_in[2];
    const float* Wk = (const float*)d_in[3];
    const float* bk = (const float*)d_in[4];
    const float* Wv = (const float*)d_in[5];
    const float* bv = (const float*)d_in[6];
    const float* Wo = (const float*)d_in[7];
    const float* bo = (const float*)d_in[8];
    float* out = (float*)d_out;

    float* f = (float*)d_ws;
    const size_t NQ = (size_t)M_ * DM;               // 1,048,576
    float* Qe    = f;
    float* Ke    = f + NQ;
    float* V     = f + 2 * NQ;
    float* Spart = f + 3 * NQ;                        // 16*16*4096 = 1M floats
    float* zpart = f + 4 * NQ;                        // 16K floats
    unsigned short* u = (unsigned short*)(f + 4 * NQ + 16384);
    unsigned short* xh = u;
    unsigned short* xl = u + NQ;
    unsigned short* wh = u + 2 * NQ;                  // 4 x 262144
    unsigned short* wl = u + 3 * NQ;
    unsigned short* jh = u + 4 * NQ;
    unsigned short* jl = u + 5 * NQ;

    prep_kernel<<<2048, 256, 0, stream>>>(x, Wq, Wk, Wv, Wo, xh, xl, wh, wl);

    dim3 gQKV(DM / TN, M_ / TM, 3);   // (8, 16, 3) = 384 blocks
    gemm_qkv_kernel<<<gQKV, 256, 0, stream>>>(xh, xl, wh, wl, bq, bk, bv, Qe, Ke, V);

    kv_stats_kernel<<<dim3(16, 16), 256, 0, stream>>>(Ke, V, Spart, zpart);

    heads_kernel<<<dim3(16, 16), 256, 0, stream>>>(Qe, Spart, zpart, jh, jl);

    dim3 gO(DM / TN, M_ / TM, 1);     // (8, 16) = 128 blocks
    gemm_out_kernel<<<gO, 256, 0, stream>>>(jh, jl, wh, wl, bo, out);
}